// Round 7
// baseline (1031.661 us; speedup 1.0000x reference)
//
#include <hip/hip_runtime.h>
#include <hip/hip_bf16.h>
#include <math.h>

#define B_ 8
#define D_ 60
#define N_ 1024
#define K_ 20
#define P1_ 8192      // B*N
#define P2_ 163840    // B*N*K

typedef __attribute__((ext_vector_type(8))) short bf16x8;
typedef __attribute__((ext_vector_type(4))) short bf16x4;
typedef __attribute__((ext_vector_type(4))) float f32x4;

__device__ inline float b2f(short s) { return __uint_as_float(((unsigned)(unsigned short)s) << 16); }
__device__ inline short f2b(float f) { __hip_bfloat16 h = __float2bfloat16(f); return *(short*)&h; }

// ---- workspace layout (bytes), all 256-aligned ----
#define OFF_IDX   0ull          // int[P2] = 655360
#define OFF_XX    655360ull     // float[P1] = 32768
#define OFF_STATS 688128ull     // A[1792], B[1792] (+slack)
#define OFF_XT    720896ull     // bf16[P1][64] = 1048576
#define OFF_WB    1769472ull    // bf16 weights
#define OFF_XC    2662400ull    // bf16[P1][512] = 8388608
#define OFF_H5    11051008ull   // bf16[P1][256] = 4194304
#define OFF_H6    15245312ull   // bf16[P1][1024] = 16777216
#define OFF_BIGA  32022528ull   // bf16[P2][128] = 41943040  (feat, later h3)
#define OFF_H1    73965568ull   // bf16[P2][64] = 20971520
#define OFF_H2    94937088ull   // bf16[P2][64] = 20971520
#define OFF_H4    115908608ull  // bf16[P2][256] = 83886080 ; pd (33.5MB) aliases here
#define OFF_PART  199794688ull  // float partial stats, max 5120 blocks * 128 * 4 = 2.6MB
// end ~202.4 MiB

#define WO1 0
#define WO2 8192
#define WO3 12288
#define WO4 20480
#define WO5 53248
#define WO6 184320

#define SO1 0
#define SO2 64
#define SO3 128
#define SO4 256
#define SO5 512
#define SO6 768
#define NCH_TOT 1792

// ---------------- xx[bn] = sum_d x^2 ----------------
__global__ __launch_bounds__(256) void k_xx(const float* __restrict__ x,
                                            float* __restrict__ xx) {
  int bn = blockIdx.x * 256 + threadIdx.x;
  int b = bn >> 10, n = bn & 1023;
  const float* xb = x + (size_t)b * D_ * N_ + n;
  float s = 0.f;
  for (int d = 0; d < D_; ++d) { float v = xb[(size_t)d * N_]; s += v * v; }
  xx[bn] = s;
}

// ---------------- pd[b][n][m] = 2*dot - xx_n - xx_m ; tiled fp32 ----------------
__global__ __launch_bounds__(256) void k_pd(const float* __restrict__ x,
                                            const float* __restrict__ xx,
                                            float* __restrict__ pd) {
  __shared__ float lnn[D_][64];
  __shared__ float lmm[D_][128];
  int tid = threadIdx.x;
  int m0 = blockIdx.x * 128, n0 = blockIdx.y * 64, b = blockIdx.z;
  const float* xb = x + (size_t)b * D_ * N_;
  #pragma unroll
  for (int i = 0; i < 15; ++i) {
    int idx = tid + i * 256;
    int d = idx >> 6, col = idx & 63;
    lnn[d][col] = xb[(size_t)d * N_ + n0 + col];
  }
  #pragma unroll
  for (int i = 0; i < 30; ++i) {
    int idx = tid + i * 256;
    int d = idx >> 7, col = idx & 127;
    lmm[d][col] = xb[(size_t)d * N_ + m0 + col];
  }
  __syncthreads();
  int tn = tid >> 5, tm = tid & 31;
  float acc[8][4];
  #pragma unroll
  for (int i = 0; i < 8; ++i)
    #pragma unroll
    for (int j = 0; j < 4; ++j) acc[i][j] = 0.f;
  for (int d = 0; d < D_; ++d) {
    f32x4 mv  = *(const f32x4*)&lmm[d][tm * 4];
    f32x4 nva = *(const f32x4*)&lnn[d][tn * 8];
    f32x4 nvb = *(const f32x4*)&lnn[d][tn * 8 + 4];
    #pragma unroll
    for (int i = 0; i < 4; ++i)
      #pragma unroll
      for (int j = 0; j < 4; ++j) {
        acc[i][j]     = fmaf(nva[i], mv[j], acc[i][j]);
        acc[4 + i][j] = fmaf(nvb[i], mv[j], acc[4 + i][j]);
      }
  }
  const float* xxb = xx + b * 1024;
  f32x4 xxm = *(const f32x4*)(xxb + m0 + tm * 4);
  #pragma unroll
  for (int i = 0; i < 8; ++i) {
    int n = n0 + tn * 8 + i;
    float xxn = xxb[n];
    f32x4 o;
    #pragma unroll
    for (int j = 0; j < 4; ++j) o[j] = 2.f * acc[i][j] - xxn - xxm[j];
    *(f32x4*)(pd + ((size_t)(b * 1024 + n) * 1024) + m0 + tm * 4) = o;
  }
}

// ---------------- selection: one wave per point, top-20 ----------------
__global__ __launch_bounds__(256) void k_sel(const float* __restrict__ pd,
                                             int* __restrict__ idxb) {
  int tid = threadIdx.x;
  int wave = tid >> 6, lane = tid & 63;
  int bn = blockIdx.x * 4 + wave;
  const float* row = pd + (size_t)bn * 1024;
  int mbase = lane * 16;
  f32x4 r0 = *(const f32x4*)(row + mbase);
  f32x4 r1 = *(const f32x4*)(row + mbase + 4);
  f32x4 r2 = *(const f32x4*)(row + mbase + 8);
  f32x4 r3 = *(const f32x4*)(row + mbase + 12);
  float v[16];
  #pragma unroll
  for (int j = 0; j < 4; ++j) { v[j] = r0[j]; v[4 + j] = r1[j]; v[8 + j] = r2[j]; v[12 + j] = r3[j]; }
  int* outp = idxb + (size_t)bn * K_;
  for (int kk = 0; kk < K_; ++kk) {
    float bv = v[0]; int bj = 0;
    #pragma unroll
    for (int j = 1; j < 16; ++j)
      if (v[j] > bv) { bv = v[j]; bj = j; }
    int bi = mbase + bj;
    #pragma unroll
    for (int off = 1; off < 64; off <<= 1) {
      float ov = __shfl_xor(bv, off);
      int   oi = __shfl_xor(bi, off);
      if (ov > bv || (ov == bv && oi < bi)) { bv = ov; bi = oi; }
    }
    if (lane == 0) outp[kk] = bi;
    #pragma unroll
    for (int j = 0; j < 16; ++j)
      if (bi == mbase + j) v[j] = -INFINITY;
  }
}

// ---------------- xt: [B][60][N] fp32 -> [P1][64] bf16 (pad 4 zeros) ----------------
__global__ __launch_bounds__(256) void k_xt(const float* __restrict__ x,
                                            short* __restrict__ xt) {
  int bn = blockIdx.x * 256 + threadIdx.x;
  int b = bn >> 10, n = bn & 1023;
  const float* xb = x + (size_t)b * D_ * N_ + n;
  short* row = xt + (size_t)bn * 64;
  for (int c = 0; c < 60; ++c) row[c] = f2b(xb[(size_t)c * N_]);
  row[60] = 0; row[61] = 0; row[62] = 0; row[63] = 0;
}

// ---------------- w1 pad: [64][120] fp32 -> [64][128] bf16 ----------------
__global__ __launch_bounds__(256) void k_w1pad(const float* __restrict__ w1,
                                               short* __restrict__ wb) {
  int t = blockIdx.x * 256 + threadIdx.x;
  int o = t >> 7, c = t & 127;
  float v = 0.f;
  if (c < 60) v = w1[o * 120 + c];
  else if (c >= 64 && c < 124) v = w1[o * 120 + 60 + (c - 64)];
  wb[t] = f2b(v);
}

// ---------------- convert w2..w6 fp32 -> bf16 ----------------
__global__ __launch_bounds__(256) void k_wcvt(const float* __restrict__ w2,
                                              const float* __restrict__ w3,
                                              const float* __restrict__ w4,
                                              const float* __restrict__ w5,
                                              const float* __restrict__ w6,
                                              short* __restrict__ wbase) {
  int t = blockIdx.x * 256 + threadIdx.x;
  if (t < 4096) wbase[WO2 + t] = f2b(w2[t]);
  else if (t < 12288) wbase[WO3 + (t - 4096)] = f2b(w3[t - 4096]);
  else if (t < 45056) wbase[WO4 + (t - 12288)] = f2b(w4[t - 12288]);
  else if (t < 176128) wbase[WO5 + (t - 45056)] = f2b(w5[t - 45056]);
  else if (t < 438272) wbase[WO6 + (t - 176128)] = f2b(w6[t - 176128]);
}

// ---------------- graph feature: [P2][128] bf16 ----------------
__global__ __launch_bounds__(256) void k_feat(const short* __restrict__ xt,
                                              const int* __restrict__ idxb,
                                              short* __restrict__ feat) {
  int t = blockIdx.x * 256 + threadIdx.x;
  int p = t >> 4, chunk = t & 15;
  int bn = p / K_;
  int nbr = (bn & ~1023) + idxb[p];
  bf16x8 o;
  if (chunk < 8) {
    bf16x8 c8 = *(const bf16x8*)(xt + (size_t)bn * 64 + chunk * 8);
    bf16x8 n8 = *(const bf16x8*)(xt + (size_t)nbr * 64 + chunk * 8);
    #pragma unroll
    for (int r = 0; r < 8; ++r) o[r] = f2b(b2f(n8[r]) - b2f(c8[r]));
  } else {
    o = *(const bf16x8*)(xt + (size_t)bn * 64 + (chunk - 8) * 8);
  }
  *(bf16x8*)(feat + (size_t)p * 128 + chunk * 8) = o;
}

// ---------------- tiled MFMA GEMM: block 128p x 64co, LDS-staged A and W ----------------
// out[P][COUT] = W[COUT][K] . act(in[P][K]) + bias, fused column stats.
// Stats: NO global atomics — per-block 128-float partial (64 sum + 64 ssq)
// stored to part[(by*gridDim.x + bx)*128 + j]; reduced later in k_bnab.
template <int K, int COUT, bool APPLY, bool STATS>
__global__ __launch_bounds__(256) void k_gemm(const short* __restrict__ in,
                                              const short* __restrict__ wb,
                                              const float* __restrict__ bias,
                                              const float* __restrict__ Ain,
                                              const float* __restrict__ Bin,
                                              float* __restrict__ part,
                                              short* __restrict__ out) {
  constexpr int PANEL = (K < 128) ? K : 128;
  constexpr int NPAN = K / PANEL;
  constexpr int CPR = PANEL / 8;            // 16B chunks per panel row
  constexpr int CSH = (CPR == 16) ? 4 : 3;
  constexpr int PK = PANEL + 8;             // padded LDS row stride (elements)
  constexpr int KS = PANEL / 32;            // MFMA k-steps per panel
  __shared__ short ldsA[128 * PK];
  __shared__ short ldsW[64 * PK];
  __shared__ float ls[128];
  int tid = threadIdx.x;
  int w = tid >> 6, lane = tid & 63;
  int ln = lane & 15, quad = lane >> 4;
  int co0 = blockIdx.y * 64;
  const short* srcA = in + (size_t)blockIdx.x * 128 * K;
  const short* srcW = wb + (size_t)co0 * K;

  f32x4 acc[4][2];
  #pragma unroll
  for (int m = 0; m < 4; ++m)
    #pragma unroll
    for (int t = 0; t < 2; ++t) acc[m][t] = (f32x4){0.f, 0.f, 0.f, 0.f};

  for (int pan = 0; pan < NPAN; ++pan) {
    int kp = pan * PANEL;
    if (pan) __syncthreads();
    // stage input panel 128 x PANEL (coalesced: 16B/lane)
    #pragma unroll
    for (int i = 0; i < CPR / 2; ++i) {
      int g = i * 256 + tid;
      int row = g >> CSH, c = g & (CPR - 1);
      bf16x8 v = *(const bf16x8*)(srcA + (size_t)row * K + kp + c * 8);
      if (APPLY) {
        f32x4 a0 = *(const f32x4*)(Ain + kp + c * 8);
        f32x4 a1 = *(const f32x4*)(Ain + kp + c * 8 + 4);
        f32x4 b0 = *(const f32x4*)(Bin + kp + c * 8);
        f32x4 b1 = *(const f32x4*)(Bin + kp + c * 8 + 4);
        #pragma unroll
        for (int j = 0; j < 8; ++j) {
          float aj = j < 4 ? a0[j] : a1[j - 4];
          float bj = j < 4 ? b0[j] : b1[j - 4];
          float f = b2f(v[j]) * aj + bj;
          f = f >= 0.f ? f : 0.2f * f;
          v[j] = f2b(f);
        }
      }
      *(bf16x8*)(ldsA + row * PK + c * 8) = v;
    }
    // stage weight panel 64 x PANEL
    #pragma unroll
    for (int i = 0; i < CPR / 4; ++i) {
      int g = i * 256 + tid;
      int row = g >> CSH, c = g & (CPR - 1);
      *(bf16x8*)(ldsW + row * PK + c * 8) =
          *(const bf16x8*)(srcW + (size_t)row * K + kp + c * 8);
    }
    __syncthreads();
    #pragma unroll
    for (int ks = 0; ks < KS; ++ks) {
      bf16x8 a[4], bfr[2];
      #pragma unroll
      for (int m = 0; m < 4; ++m)
        a[m] = *(const bf16x8*)(ldsW + (m * 16 + ln) * PK + ks * 32 + quad * 8);
      #pragma unroll
      for (int t = 0; t < 2; ++t)
        bfr[t] = *(const bf16x8*)(ldsA + (w * 32 + t * 16 + ln) * PK + ks * 32 + quad * 8);
      #pragma unroll
      for (int m = 0; m < 4; ++m)
        #pragma unroll
        for (int t = 0; t < 2; ++t)
          acc[m][t] = __builtin_amdgcn_mfma_f32_16x16x32_bf16(a[m], bfr[t], acc[m][t], 0, 0, 0);
    }
  }
  // epilogue: bias + store
  #pragma unroll
  for (int m = 0; m < 4; ++m) {
    f32x4 bs = *(const f32x4*)(bias + co0 + m * 16 + quad * 4);
    #pragma unroll
    for (int t = 0; t < 2; ++t)
      #pragma unroll
      for (int r = 0; r < 4; ++r) acc[m][t][r] += bs[r];
  }
  #pragma unroll
  for (int m = 0; m < 4; ++m)
    #pragma unroll
    for (int t = 0; t < 2; ++t) {
      int p = blockIdx.x * 128 + w * 32 + t * 16 + ln;
      bf16x4 o;
      #pragma unroll
      for (int r = 0; r < 4; ++r) o[r] = f2b(acc[m][t][r]);
      *(bf16x4*)(out + (size_t)p * COUT + co0 + m * 16 + quad * 4) = o;
    }
  // fused BN stats partial (once per block, no global atomics)
  if (STATS) {
    __syncthreads();
    if (tid < 128) ls[tid] = 0.f;
    __syncthreads();
    #pragma unroll
    for (int m = 0; m < 4; ++m)
      #pragma unroll
      for (int r = 0; r < 4; ++r) {
        float v0 = acc[m][0][r], v1 = acc[m][1][r];
        float s = v0 + v1, ss = v0 * v0 + v1 * v1;
        #pragma unroll
        for (int off = 1; off < 16; off <<= 1) {
          s += __shfl_xor(s, off); ss += __shfl_xor(ss, off);
        }
        if (ln == 0) {
          atomicAdd(&ls[m * 16 + quad * 4 + r], s);
          atomicAdd(&ls[64 + m * 16 + quad * 4 + r], ss);
        }
      }
    __syncthreads();
    if (tid < 128)
      part[((size_t)blockIdx.y * gridDim.x + blockIdx.x) * 128 + tid] = ls[tid];
  }
}

// ---------------- reduce partials -> A = g*rsqrt(var+eps), B = be - mean*A ----------------
// grid.x = COUT/64 (co-chunks); NB = gemm gridDim.x (partials per co-chunk)
__global__ __launch_bounds__(256) void k_bnab(const float* __restrict__ part, int NB,
                                              const float* __restrict__ g,
                                              const float* __restrict__ be,
                                              float* __restrict__ A,
                                              float* __restrict__ Bp, float inv) {
  __shared__ float red[256];
  int tid = threadIdx.x;
  int j = tid & 127, h = tid >> 7;
  const float* p = part + (size_t)blockIdx.x * NB * 128;
  float s = 0.f;
  for (int bx = h; bx < NB; bx += 2) s += p[(size_t)bx * 128 + j];
  red[tid] = s;
  __syncthreads();
  if (tid < 128) red[tid] = red[tid] + red[tid + 128];
  __syncthreads();
  if (tid < 64) {
    int c = blockIdx.x * 64 + tid;
    float m = red[tid] * inv;
    float v = red[64 + tid] * inv - m * m;
    float a = g[c] * rsqrtf(v + 1e-5f);
    A[c] = a; Bp[c] = be[c] - m * a;
  }
}

// ---------------- BN+lrelu + max over k -> xcat (no writeback) ----------------
template <int C>
__global__ __launch_bounds__(256) void k_apply_max(const short* __restrict__ h,
                                                   const float* __restrict__ A,
                                                   const float* __restrict__ Bp,
                                                   short* __restrict__ xcat, int xoff) {
  constexpr int CH = C / 4;
  int t = blockIdx.x * 256 + threadIdx.x;
  int bn = t / CH;
  int c0 = (t % CH) * 4;
  f32x4 a = *(const f32x4*)(A + c0);
  f32x4 b = *(const f32x4*)(Bp + c0);
  float m0 = -INFINITY, m1 = -INFINITY, m2 = -INFINITY, m3 = -INFINITY;
  size_t base = (size_t)bn * K_ * C + c0;
  for (int j = 0; j < K_; ++j) {
    bf16x4 v = *(const bf16x4*)(h + base + (size_t)j * C);
    float f0 = b2f(v[0]) * a[0] + b[0]; f0 = f0 >= 0.f ? f0 : 0.2f * f0;
    float f1 = b2f(v[1]) * a[1] + b[1]; f1 = f1 >= 0.f ? f1 : 0.2f * f1;
    float f2 = b2f(v[2]) * a[2] + b[2]; f2 = f2 >= 0.f ? f2 : 0.2f * f2;
    float f3 = b2f(v[3]) * a[3] + b[3]; f3 = f3 >= 0.f ? f3 : 0.2f * f3;
    m0 = fmaxf(m0, f0); m1 = fmaxf(m1, f1); m2 = fmaxf(m2, f2); m3 = fmaxf(m3, f3);
  }
  bf16x4 o;
  o[0] = f2b(m0); o[1] = f2b(m1); o[2] = f2b(m2); o[3] = f2b(m3);
  *(bf16x4*)(xcat + (size_t)bn * 512 + xoff + c0) = o;
}

// ---------------- final: BN+lrelu bf16 [P1][1024] -> fp32 out ----------------
__global__ __launch_bounds__(256) void k_apply_out(const short* __restrict__ h,
                                                   const float* __restrict__ A,
                                                   const float* __restrict__ Bp,
                                                   float* __restrict__ out) {
  int t = blockIdx.x * 256 + threadIdx.x;
  int c0 = (t & 255) * 4;
  f32x4 a = *(const f32x4*)(A + c0);
  f32x4 b = *(const f32x4*)(Bp + c0);
  bf16x4 v = *(const bf16x4*)(h + (size_t)t * 4);
  f32x4 o;
  #pragma unroll
  for (int r = 0; r < 4; ++r) {
    float f = b2f(v[r]) * a[r] + b[r];
    o[r] = f >= 0.f ? f : 0.2f * f;
  }
  *(f32x4*)(out + (size_t)t * 4) = o;
}

extern "C" void kernel_launch(void* const* d_in, const int* in_sizes, int n_in,
                              void* d_out, int out_size, void* d_ws, size_t ws_size,
                              hipStream_t stream) {
  const float* x   = (const float*)d_in[0];
  const float* w1  = (const float*)d_in[1];
  const float* b1  = (const float*)d_in[2];
  const float* g1  = (const float*)d_in[3];
  const float* be1 = (const float*)d_in[4];
  const float* w2  = (const float*)d_in[5];
  const float* b2  = (const float*)d_in[6];
  const float* g2  = (const float*)d_in[7];
  const float* be2 = (const float*)d_in[8];
  const float* w3  = (const float*)d_in[9];
  const float* b3  = (const float*)d_in[10];
  const float* g3  = (const float*)d_in[11];
  const float* be3 = (const float*)d_in[12];
  const float* w4  = (const float*)d_in[13];
  const float* b4  = (const float*)d_in[14];
  const float* g4  = (const float*)d_in[15];
  const float* be4 = (const float*)d_in[16];
  const float* w5  = (const float*)d_in[17];
  const float* b5  = (const float*)d_in[18];
  const float* g5  = (const float*)d_in[19];
  const float* be5 = (const float*)d_in[20];
  const float* w6  = (const float*)d_in[21];
  const float* b6  = (const float*)d_in[22];
  const float* g6  = (const float*)d_in[23];
  const float* be6 = (const float*)d_in[24];
  float* out = (float*)d_out;
  char* ws = (char*)d_ws;

  int*   idxb = (int*)(ws + OFF_IDX);
  float* xx   = (float*)(ws + OFF_XX);
  float* Aall = (float*)(ws + OFF_STATS);
  float* Ball = Aall + NCH_TOT;
  short* xt   = (short*)(ws + OFF_XT);
  short* wbb  = (short*)(ws + OFF_WB);
  short* xcat = (short*)(ws + OFF_XC);
  short* h5   = (short*)(ws + OFF_H5);
  short* h6   = (short*)(ws + OFF_H6);
  short* feat = (short*)(ws + OFF_BIGA);
  short* h1   = (short*)(ws + OFF_H1);
  short* h2   = (short*)(ws + OFF_H2);
  short* h3   = (short*)(ws + OFF_BIGA);
  short* h4   = (short*)(ws + OFF_H4);
  float* pd   = (float*)(ws + OFF_H4);   // aliases h4; consumed before h4 written
  float* part = (float*)(ws + OFF_PART); // reused serially by each layer

  k_xx <<<P1_ / 256, 256, 0, stream>>>(x, xx);
  k_pd <<<dim3(8, 16, 8), 256, 0, stream>>>(x, xx, pd);
  k_sel<<<P1_ / 4, 256, 0, stream>>>(pd, idxb);
  k_xt <<<P1_ / 256, 256, 0, stream>>>(x, xt);
  k_w1pad<<<32, 256, 0, stream>>>(w1, wbb + WO1);
  k_wcvt<<<1712, 256, 0, stream>>>(w2, w3, w4, w5, w6, wbb);
  k_feat<<<P2_ * 16 / 256, 256, 0, stream>>>(xt, idxb, feat);

  // layer 1: feat[P2][128] x w1 -> h1 (raw) + stats partials
  k_gemm<128, 64, false, true><<<dim3(P2_ / 128, 1), 256, 0, stream>>>(
      feat, wbb + WO1, b1, nullptr, nullptr, part, h1);
  k_bnab<<<1, 256, 0, stream>>>(part, P2_ / 128, g1, be1, Aall + SO1, Ball + SO1, 1.f / P2_);
  k_apply_max<64><<<P1_ * 16 / 256, 256, 0, stream>>>(h1, Aall + SO1, Ball + SO1, xcat, 0);

  // layer 2: act(h1) x w2 -> h2 (raw) + stats partials
  k_gemm<64, 64, true, true><<<dim3(P2_ / 128, 1), 256, 0, stream>>>(
      h1, wbb + WO2, b2, Aall + SO1, Ball + SO1, part, h2);
  k_bnab<<<1, 256, 0, stream>>>(part, P2_ / 128, g2, be2, Aall + SO2, Ball + SO2, 1.f / P2_);
  k_apply_max<64><<<P1_ * 16 / 256, 256, 0, stream>>>(h2, Aall + SO2, Ball + SO2, xcat, 64);

  // layer 3: act(h2) x w3 -> h3 (raw) + stats partials
  k_gemm<64, 128, true, true><<<dim3(P2_ / 128, 2), 256, 0, stream>>>(
      h2, wbb + WO3, b3, Aall + SO2, Ball + SO2, part, h3);
  k_bnab<<<2, 256, 0, stream>>>(part, P2_ / 128, g3, be3, Aall + SO3, Ball + SO3, 1.f / P2_);
  k_apply_max<128><<<P1_ * 32 / 256, 256, 0, stream>>>(h3, Aall + SO3, Ball + SO3, xcat, 128);

  // layer 4: act(h3) x w4 -> h4 (raw) + stats partials
  k_gemm<128, 256, true, true><<<dim3(P2_ / 128, 4), 256, 0, stream>>>(
      h3, wbb + WO4, b4, Aall + SO3, Ball + SO3, part, h4);
  k_bnab<<<4, 256, 0, stream>>>(part, P2_ / 128, g4, be4, Aall + SO4, Ball + SO4, 1.f / P2_);
  k_apply_max<256><<<P1_ * 64 / 256, 256, 0, stream>>>(h4, Aall + SO4, Ball + SO4, xcat, 256);

  // layer 5: xcat x w5 -> h5 (raw) + stats partials; K=512 panels
  k_gemm<512, 256, false, true><<<dim3(P1_ / 128, 4), 256, 0, stream>>>(
      xcat, wbb + WO5, b5, nullptr, nullptr, part, h5);
  k_bnab<<<4, 256, 0, stream>>>(part, P1_ / 128, g5, be5, Aall + SO5, Ball + SO5, 1.f / P1_);

  // layer 6: act(h5) x w6 -> h6 (raw) + stats partials; K=256 panels
  k_gemm<256, 1024, true, true><<<dim3(P1_ / 128, 16), 256, 0, stream>>>(
      h5, wbb + WO6, b6, Aall + SO5, Ball + SO5, part, h6);
  k_bnab<<<16, 256, 0, stream>>>(part, P1_ / 128, g6, be6, Aall + SO6, Ball + SO6, 1.f / P1_);
  k_apply_out<<<P1_ * 256 / 256, 256, 0, stream>>>(h6, Aall + SO6, Ball + SO6, out);

  (void)in_sizes; (void)n_in; (void)out_size; (void)ws_size;
}

// Round 8
// 446.105 us; speedup vs baseline: 2.3126x; 2.3126x over previous
//
#include <hip/hip_runtime.h>
#include <hip/hip_bf16.h>
#include <math.h>

#define B_ 8
#define D_ 60
#define N_ 1024
#define K_ 20
#define P1_ 8192      // B*N
#define P2_ 163840    // B*N*K

typedef __attribute__((ext_vector_type(8))) short bf16x8;
typedef __attribute__((ext_vector_type(4))) short bf16x4;
typedef __attribute__((ext_vector_type(4))) float f32x4;

__device__ inline float b2f(short s) { return __uint_as_float(((unsigned)(unsigned short)s) << 16); }
__device__ inline short f2b(float f) { __hip_bfloat16 h = __float2bfloat16(f); return *(short*)&h; }

// ---- workspace layout (bytes), all 256-aligned ----
#define OFF_IDX   0ull          // int[P2] = 655360
#define OFF_XX    655360ull     // float[P1] = 32768
#define OFF_STATS 688128ull     // A[1792], B[1792] (+slack)
#define OFF_XT    720896ull     // bf16[P1][64] = 1048576
#define OFF_WB    1769472ull    // bf16 weights
#define OFF_XC    2662400ull    // bf16[P1][512] = 8388608
#define OFF_H5    11051008ull   // bf16[P1][256] = 4194304
#define OFF_H6    15245312ull   // bf16[P1][1024] = 16777216
#define OFF_BIGA  32022528ull   // bf16[P2][128] = 41943040  (feat, later h3)
#define OFF_H1    73965568ull   // bf16[P2][64] = 20971520
#define OFF_H2    94937088ull   // bf16[P2][64] = 20971520
#define OFF_H4    115908608ull  // bf16[P2][256] = 83886080 ; pd (33.5MB) aliases here
#define OFF_PART  199794688ull  // float partial stats, max 4*1280*128*4 = 2.62MB
#define OFF_PART2 202444800ull  // float stage-2 partials, 4*32*128*4 = 64KB
// end ~202.6 MiB

#define WO1 0
#define WO2 8192
#define WO3 12288
#define WO4 20480
#define WO5 53248
#define WO6 184320

#define SO1 0
#define SO2 64
#define SO3 128
#define SO4 256
#define SO5 512
#define SO6 768
#define NCH_TOT 1792

// ---------------- xx[bn] = sum_d x^2 ----------------
__global__ __launch_bounds__(256) void k_xx(const float* __restrict__ x,
                                            float* __restrict__ xx) {
  int bn = blockIdx.x * 256 + threadIdx.x;
  int b = bn >> 10, n = bn & 1023;
  const float* xb = x + (size_t)b * D_ * N_ + n;
  float s = 0.f;
  for (int d = 0; d < D_; ++d) { float v = xb[(size_t)d * N_]; s += v * v; }
  xx[bn] = s;
}

// ---------------- pd[b][n][m] = 2*dot - xx_n - xx_m ; tiled fp32 ----------------
__global__ __launch_bounds__(256) void k_pd(const float* __restrict__ x,
                                            const float* __restrict__ xx,
                                            float* __restrict__ pd) {
  __shared__ float lnn[D_][64];
  __shared__ float lmm[D_][128];
  int tid = threadIdx.x;
  int m0 = blockIdx.x * 128, n0 = blockIdx.y * 64, b = blockIdx.z;
  const float* xb = x + (size_t)b * D_ * N_;
  #pragma unroll
  for (int i = 0; i < 15; ++i) {
    int idx = tid + i * 256;
    int d = idx >> 6, col = idx & 63;
    lnn[d][col] = xb[(size_t)d * N_ + n0 + col];
  }
  #pragma unroll
  for (int i = 0; i < 30; ++i) {
    int idx = tid + i * 256;
    int d = idx >> 7, col = idx & 127;
    lmm[d][col] = xb[(size_t)d * N_ + m0 + col];
  }
  __syncthreads();
  int tn = tid >> 5, tm = tid & 31;
  float acc[8][4];
  #pragma unroll
  for (int i = 0; i < 8; ++i)
    #pragma unroll
    for (int j = 0; j < 4; ++j) acc[i][j] = 0.f;
  for (int d = 0; d < D_; ++d) {
    f32x4 mv  = *(const f32x4*)&lmm[d][tm * 4];
    f32x4 nva = *(const f32x4*)&lnn[d][tn * 8];
    f32x4 nvb = *(const f32x4*)&lnn[d][tn * 8 + 4];
    #pragma unroll
    for (int i = 0; i < 4; ++i)
      #pragma unroll
      for (int j = 0; j < 4; ++j) {
        acc[i][j]     = fmaf(nva[i], mv[j], acc[i][j]);
        acc[4 + i][j] = fmaf(nvb[i], mv[j], acc[4 + i][j]);
      }
  }
  const float* xxb = xx + b * 1024;
  f32x4 xxm = *(const f32x4*)(xxb + m0 + tm * 4);
  #pragma unroll
  for (int i = 0; i < 8; ++i) {
    int n = n0 + tn * 8 + i;
    float xxn = xxb[n];
    f32x4 o;
    #pragma unroll
    for (int j = 0; j < 4; ++j) o[j] = 2.f * acc[i][j] - xxn - xxm[j];
    *(f32x4*)(pd + ((size_t)(b * 1024 + n) * 1024) + m0 + tm * 4) = o;
  }
}

// ---------------- selection: one wave per point, top-20 ----------------
__global__ __launch_bounds__(256) void k_sel(const float* __restrict__ pd,
                                             int* __restrict__ idxb) {
  int tid = threadIdx.x;
  int wave = tid >> 6, lane = tid & 63;
  int bn = blockIdx.x * 4 + wave;
  const float* row = pd + (size_t)bn * 1024;
  int mbase = lane * 16;
  f32x4 r0 = *(const f32x4*)(row + mbase);
  f32x4 r1 = *(const f32x4*)(row + mbase + 4);
  f32x4 r2 = *(const f32x4*)(row + mbase + 8);
  f32x4 r3 = *(const f32x4*)(row + mbase + 12);
  float v[16];
  #pragma unroll
  for (int j = 0; j < 4; ++j) { v[j] = r0[j]; v[4 + j] = r1[j]; v[8 + j] = r2[j]; v[12 + j] = r3[j]; }
  int* outp = idxb + (size_t)bn * K_;
  for (int kk = 0; kk < K_; ++kk) {
    float bv = v[0]; int bj = 0;
    #pragma unroll
    for (int j = 1; j < 16; ++j)
      if (v[j] > bv) { bv = v[j]; bj = j; }
    int bi = mbase + bj;
    #pragma unroll
    for (int off = 1; off < 64; off <<= 1) {
      float ov = __shfl_xor(bv, off);
      int   oi = __shfl_xor(bi, off);
      if (ov > bv || (ov == bv && oi < bi)) { bv = ov; bi = oi; }
    }
    if (lane == 0) outp[kk] = bi;
    #pragma unroll
    for (int j = 0; j < 16; ++j)
      if (bi == mbase + j) v[j] = -INFINITY;
  }
}

// ---------------- xt: [B][60][N] fp32 -> [P1][64] bf16 (pad 4 zeros) ----------------
__global__ __launch_bounds__(256) void k_xt(const float* __restrict__ x,
                                            short* __restrict__ xt) {
  int bn = blockIdx.x * 256 + threadIdx.x;
  int b = bn >> 10, n = bn & 1023;
  const float* xb = x + (size_t)b * D_ * N_ + n;
  short* row = xt + (size_t)bn * 64;
  for (int c = 0; c < 60; ++c) row[c] = f2b(xb[(size_t)c * N_]);
  row[60] = 0; row[61] = 0; row[62] = 0; row[63] = 0;
}

// ---------------- w1 pad: [64][120] fp32 -> [64][128] bf16 ----------------
__global__ __launch_bounds__(256) void k_w1pad(const float* __restrict__ w1,
                                               short* __restrict__ wb) {
  int t = blockIdx.x * 256 + threadIdx.x;
  int o = t >> 7, c = t & 127;
  float v = 0.f;
  if (c < 60) v = w1[o * 120 + c];
  else if (c >= 64 && c < 124) v = w1[o * 120 + 60 + (c - 64)];
  wb[t] = f2b(v);
}

// ---------------- convert w2..w6 fp32 -> bf16 ----------------
__global__ __launch_bounds__(256) void k_wcvt(const float* __restrict__ w2,
                                              const float* __restrict__ w3,
                                              const float* __restrict__ w4,
                                              const float* __restrict__ w5,
                                              const float* __restrict__ w6,
                                              short* __restrict__ wbase) {
  int t = blockIdx.x * 256 + threadIdx.x;
  if (t < 4096) wbase[WO2 + t] = f2b(w2[t]);
  else if (t < 12288) wbase[WO3 + (t - 4096)] = f2b(w3[t - 4096]);
  else if (t < 45056) wbase[WO4 + (t - 12288)] = f2b(w4[t - 12288]);
  else if (t < 176128) wbase[WO5 + (t - 45056)] = f2b(w5[t - 45056]);
  else if (t < 438272) wbase[WO6 + (t - 176128)] = f2b(w6[t - 176128]);
}

// ---------------- graph feature: [P2][128] bf16 ----------------
__global__ __launch_bounds__(256) void k_feat(const short* __restrict__ xt,
                                              const int* __restrict__ idxb,
                                              short* __restrict__ feat) {
  int t = blockIdx.x * 256 + threadIdx.x;
  int p = t >> 4, chunk = t & 15;
  int bn = p / K_;
  int nbr = (bn & ~1023) + idxb[p];
  bf16x8 o;
  if (chunk < 8) {
    bf16x8 c8 = *(const bf16x8*)(xt + (size_t)bn * 64 + chunk * 8);
    bf16x8 n8 = *(const bf16x8*)(xt + (size_t)nbr * 64 + chunk * 8);
    #pragma unroll
    for (int r = 0; r < 8; ++r) o[r] = f2b(b2f(n8[r]) - b2f(c8[r]));
  } else {
    o = *(const bf16x8*)(xt + (size_t)bn * 64 + (chunk - 8) * 8);
  }
  *(bf16x8*)(feat + (size_t)p * 128 + chunk * 8) = o;
}

// ---------------- tiled MFMA GEMM: block 128p x 64co, LDS-staged A and W ----------------
// out[P][COUT] = W[COUT][K] . act(in[P][K]) + bias, fused column stats.
// Stats: per-block 128-float partial (64 sum + 64 ssq), no global atomics.
template <int K, int COUT, bool APPLY, bool STATS>
__global__ __launch_bounds__(256) void k_gemm(const short* __restrict__ in,
                                              const short* __restrict__ wb,
                                              const float* __restrict__ bias,
                                              const float* __restrict__ Ain,
                                              const float* __restrict__ Bin,
                                              float* __restrict__ part,
                                              short* __restrict__ out) {
  constexpr int PANEL = (K < 128) ? K : 128;
  constexpr int NPAN = K / PANEL;
  constexpr int CPR = PANEL / 8;            // 16B chunks per panel row
  constexpr int CSH = (CPR == 16) ? 4 : 3;
  constexpr int PK = PANEL + 8;             // padded LDS row stride (elements)
  constexpr int KS = PANEL / 32;            // MFMA k-steps per panel
  __shared__ short ldsA[128 * PK];
  __shared__ short ldsW[64 * PK];
  __shared__ float ls[128];
  int tid = threadIdx.x;
  int w = tid >> 6, lane = tid & 63;
  int ln = lane & 15, quad = lane >> 4;
  int co0 = blockIdx.y * 64;
  const short* srcA = in + (size_t)blockIdx.x * 128 * K;
  const short* srcW = wb + (size_t)co0 * K;

  f32x4 acc[4][2];
  #pragma unroll
  for (int m = 0; m < 4; ++m)
    #pragma unroll
    for (int t = 0; t < 2; ++t) acc[m][t] = (f32x4){0.f, 0.f, 0.f, 0.f};

  for (int pan = 0; pan < NPAN; ++pan) {
    int kp = pan * PANEL;
    if (pan) __syncthreads();
    // stage input panel 128 x PANEL (coalesced: 16B/lane)
    #pragma unroll
    for (int i = 0; i < CPR / 2; ++i) {
      int g = i * 256 + tid;
      int row = g >> CSH, c = g & (CPR - 1);
      bf16x8 v = *(const bf16x8*)(srcA + (size_t)row * K + kp + c * 8);
      if (APPLY) {
        f32x4 a0 = *(const f32x4*)(Ain + kp + c * 8);
        f32x4 a1 = *(const f32x4*)(Ain + kp + c * 8 + 4);
        f32x4 b0 = *(const f32x4*)(Bin + kp + c * 8);
        f32x4 b1 = *(const f32x4*)(Bin + kp + c * 8 + 4);
        #pragma unroll
        for (int j = 0; j < 8; ++j) {
          float aj = j < 4 ? a0[j] : a1[j - 4];
          float bj = j < 4 ? b0[j] : b1[j - 4];
          float f = b2f(v[j]) * aj + bj;
          f = f >= 0.f ? f : 0.2f * f;
          v[j] = f2b(f);
        }
      }
      *(bf16x8*)(ldsA + row * PK + c * 8) = v;
    }
    // stage weight panel 64 x PANEL
    #pragma unroll
    for (int i = 0; i < CPR / 4; ++i) {
      int g = i * 256 + tid;
      int row = g >> CSH, c = g & (CPR - 1);
      *(bf16x8*)(ldsW + row * PK + c * 8) =
          *(const bf16x8*)(srcW + (size_t)row * K + kp + c * 8);
    }
    __syncthreads();
    #pragma unroll
    for (int ks = 0; ks < KS; ++ks) {
      bf16x8 a[4], bfr[2];
      #pragma unroll
      for (int m = 0; m < 4; ++m)
        a[m] = *(const bf16x8*)(ldsW + (m * 16 + ln) * PK + ks * 32 + quad * 8);
      #pragma unroll
      for (int t = 0; t < 2; ++t)
        bfr[t] = *(const bf16x8*)(ldsA + (w * 32 + t * 16 + ln) * PK + ks * 32 + quad * 8);
      #pragma unroll
      for (int m = 0; m < 4; ++m)
        #pragma unroll
        for (int t = 0; t < 2; ++t)
          acc[m][t] = __builtin_amdgcn_mfma_f32_16x16x32_bf16(a[m], bfr[t], acc[m][t], 0, 0, 0);
    }
  }
  // epilogue: bias + store
  #pragma unroll
  for (int m = 0; m < 4; ++m) {
    f32x4 bs = *(const f32x4*)(bias + co0 + m * 16 + quad * 4);
    #pragma unroll
    for (int t = 0; t < 2; ++t)
      #pragma unroll
      for (int r = 0; r < 4; ++r) acc[m][t][r] += bs[r];
  }
  #pragma unroll
  for (int m = 0; m < 4; ++m)
    #pragma unroll
    for (int t = 0; t < 2; ++t) {
      int p = blockIdx.x * 128 + w * 32 + t * 16 + ln;
      bf16x4 o;
      #pragma unroll
      for (int r = 0; r < 4; ++r) o[r] = f2b(acc[m][t][r]);
      *(bf16x4*)(out + (size_t)p * COUT + co0 + m * 16 + quad * 4) = o;
    }
  // fused BN stats partial (once per block, no global atomics)
  if (STATS) {
    __syncthreads();
    if (tid < 128) ls[tid] = 0.f;
    __syncthreads();
    #pragma unroll
    for (int m = 0; m < 4; ++m)
      #pragma unroll
      for (int r = 0; r < 4; ++r) {
        float v0 = acc[m][0][r], v1 = acc[m][1][r];
        float s = v0 + v1, ss = v0 * v0 + v1 * v1;
        #pragma unroll
        for (int off = 1; off < 16; off <<= 1) {
          s += __shfl_xor(s, off); ss += __shfl_xor(ss, off);
        }
        if (ln == 0) {
          atomicAdd(&ls[m * 16 + quad * 4 + r], s);
          atomicAdd(&ls[64 + m * 16 + quad * 4 + r], ss);
        }
      }
    __syncthreads();
    if (tid < 128)
      part[((size_t)blockIdx.y * gridDim.x + blockIdx.x) * 128 + tid] = ls[tid];
  }
}

// ---------------- stage-1 reduction: part[cc][NB][128] -> part2[cc][32][128] ----------------
// grid (co_chunks, 32); each block reduces a contiguous NB/32-row slab.
__global__ __launch_bounds__(256) void k_red(const float* __restrict__ part, int NB,
                                             float* __restrict__ part2) {
  int cc = blockIdx.x, by = blockIdx.y;
  int tid = threadIdx.x;
  int rg = tid >> 5;        // row group 0..7
  int c4 = (tid & 31) * 4;  // col offset
  int chunk = NB >> 5;      // rows per block
  const float* p = part + ((size_t)cc * NB + (size_t)by * chunk) * 128;
  f32x4 acc = (f32x4){0.f, 0.f, 0.f, 0.f};
  for (int r = rg; r < chunk; r += 8) {
    f32x4 v = *(const f32x4*)(p + (size_t)r * 128 + c4);
    acc[0] += v[0]; acc[1] += v[1]; acc[2] += v[2]; acc[3] += v[3];
  }
  __shared__ float lds[1024];
  *(f32x4*)(lds + tid * 4) = acc;
  __syncthreads();
  if (tid < 32) {
    f32x4 s = (f32x4){0.f, 0.f, 0.f, 0.f};
    #pragma unroll
    for (int g = 0; g < 8; ++g) {
      f32x4 v = *(const f32x4*)(lds + (g * 32 + tid) * 4);
      s[0] += v[0]; s[1] += v[1]; s[2] += v[2]; s[3] += v[3];
    }
    *(f32x4*)(part2 + ((size_t)cc * 32 + by) * 128 + tid * 4) = s;
  }
}

// ---------------- reduce partials -> A = g*rsqrt(var+eps), B = be - mean*A ----------------
// grid.x = COUT/64 (co-chunks); NB = partial rows per co-chunk
__global__ __launch_bounds__(256) void k_bnab(const float* __restrict__ part, int NB,
                                              const float* __restrict__ g,
                                              const float* __restrict__ be,
                                              float* __restrict__ A,
                                              float* __restrict__ Bp, float inv) {
  __shared__ float red[256];
  int tid = threadIdx.x;
  int j = tid & 127, h = tid >> 7;
  const float* p = part + (size_t)blockIdx.x * NB * 128;
  float s = 0.f;
  for (int bx = h; bx < NB; bx += 2) s += p[(size_t)bx * 128 + j];
  red[tid] = s;
  __syncthreads();
  if (tid < 128) red[tid] = red[tid] + red[tid + 128];
  __syncthreads();
  if (tid < 64) {
    int c = blockIdx.x * 64 + tid;
    float m = red[tid] * inv;
    float v = red[64 + tid] * inv - m * m;
    float a = g[c] * rsqrtf(v + 1e-5f);
    A[c] = a; Bp[c] = be[c] - m * a;
  }
}

// ---------------- BN+lrelu + max over k -> xcat (no writeback) ----------------
template <int C>
__global__ __launch_bounds__(256) void k_apply_max(const short* __restrict__ h,
                                                   const float* __restrict__ A,
                                                   const float* __restrict__ Bp,
                                                   short* __restrict__ xcat, int xoff) {
  constexpr int CH = C / 4;
  int t = blockIdx.x * 256 + threadIdx.x;
  int bn = t / CH;
  int c0 = (t % CH) * 4;
  f32x4 a = *(const f32x4*)(A + c0);
  f32x4 b = *(const f32x4*)(Bp + c0);
  float m0 = -INFINITY, m1 = -INFINITY, m2 = -INFINITY, m3 = -INFINITY;
  size_t base = (size_t)bn * K_ * C + c0;
  for (int j = 0; j < K_; ++j) {
    bf16x4 v = *(const bf16x4*)(h + base + (size_t)j * C);
    float f0 = b2f(v[0]) * a[0] + b[0]; f0 = f0 >= 0.f ? f0 : 0.2f * f0;
    float f1 = b2f(v[1]) * a[1] + b[1]; f1 = f1 >= 0.f ? f1 : 0.2f * f1;
    float f2 = b2f(v[2]) * a[2] + b[2]; f2 = f2 >= 0.f ? f2 : 0.2f * f2;
    float f3 = b2f(v[3]) * a[3] + b[3]; f3 = f3 >= 0.f ? f3 : 0.2f * f3;
    m0 = fmaxf(m0, f0); m1 = fmaxf(m1, f1); m2 = fmaxf(m2, f2); m3 = fmaxf(m3, f3);
  }
  bf16x4 o;
  o[0] = f2b(m0); o[1] = f2b(m1); o[2] = f2b(m2); o[3] = f2b(m3);
  *(bf16x4*)(xcat + (size_t)bn * 512 + xoff + c0) = o;
}

// ---------------- final: BN+lrelu bf16 [P1][1024] -> fp32 out ----------------
__global__ __launch_bounds__(256) void k_apply_out(const short* __restrict__ h,
                                                   const float* __restrict__ A,
                                                   const float* __restrict__ Bp,
                                                   float* __restrict__ out) {
  int t = blockIdx.x * 256 + threadIdx.x;
  int c0 = (t & 255) * 4;
  f32x4 a = *(const f32x4*)(A + c0);
  f32x4 b = *(const f32x4*)(Bp + c0);
  bf16x4 v = *(const bf16x4*)(h + (size_t)t * 4);
  f32x4 o;
  #pragma unroll
  for (int r = 0; r < 4; ++r) {
    float f = b2f(v[r]) * a[r] + b[r];
    o[r] = f >= 0.f ? f : 0.2f * f;
  }
  *(f32x4*)(out + (size_t)t * 4) = o;
}

extern "C" void kernel_launch(void* const* d_in, const int* in_sizes, int n_in,
                              void* d_out, int out_size, void* d_ws, size_t ws_size,
                              hipStream_t stream) {
  const float* x   = (const float*)d_in[0];
  const float* w1  = (const float*)d_in[1];
  const float* b1  = (const float*)d_in[2];
  const float* g1  = (const float*)d_in[3];
  const float* be1 = (const float*)d_in[4];
  const float* w2  = (const float*)d_in[5];
  const float* b2  = (const float*)d_in[6];
  const float* g2  = (const float*)d_in[7];
  const float* be2 = (const float*)d_in[8];
  const float* w3  = (const float*)d_in[9];
  const float* b3  = (const float*)d_in[10];
  const float* g3  = (const float*)d_in[11];
  const float* be3 = (const float*)d_in[12];
  const float* w4  = (const float*)d_in[13];
  const float* b4  = (const float*)d_in[14];
  const float* g4  = (const float*)d_in[15];
  const float* be4 = (const float*)d_in[16];
  const float* w5  = (const float*)d_in[17];
  const float* b5  = (const float*)d_in[18];
  const float* g5  = (const float*)d_in[19];
  const float* be5 = (const float*)d_in[20];
  const float* w6  = (const float*)d_in[21];
  const float* b6  = (const float*)d_in[22];
  const float* g6  = (const float*)d_in[23];
  const float* be6 = (const float*)d_in[24];
  float* out = (float*)d_out;
  char* ws = (char*)d_ws;

  int*   idxb = (int*)(ws + OFF_IDX);
  float* xx   = (float*)(ws + OFF_XX);
  float* Aall = (float*)(ws + OFF_STATS);
  float* Ball = Aall + NCH_TOT;
  short* xt   = (short*)(ws + OFF_XT);
  short* wbb  = (short*)(ws + OFF_WB);
  short* xcat = (short*)(ws + OFF_XC);
  short* h5   = (short*)(ws + OFF_H5);
  short* h6   = (short*)(ws + OFF_H6);
  short* feat = (short*)(ws + OFF_BIGA);
  short* h1   = (short*)(ws + OFF_H1);
  short* h2   = (short*)(ws + OFF_H2);
  short* h3   = (short*)(ws + OFF_BIGA);
  short* h4   = (short*)(ws + OFF_H4);
  float* pd    = (float*)(ws + OFF_H4);    // aliases h4; consumed before h4 written
  float* part  = (float*)(ws + OFF_PART);  // reused serially by each layer
  float* part2 = (float*)(ws + OFF_PART2);

  k_xx <<<P1_ / 256, 256, 0, stream>>>(x, xx);
  k_pd <<<dim3(8, 16, 8), 256, 0, stream>>>(x, xx, pd);
  k_sel<<<P1_ / 4, 256, 0, stream>>>(pd, idxb);
  k_xt <<<P1_ / 256, 256, 0, stream>>>(x, xt);
  k_w1pad<<<32, 256, 0, stream>>>(w1, wbb + WO1);
  k_wcvt<<<1712, 256, 0, stream>>>(w2, w3, w4, w5, w6, wbb);
  k_feat<<<P2_ * 16 / 256, 256, 0, stream>>>(xt, idxb, feat);

  // layer 1: feat[P2][128] x w1 -> h1 (raw) + stats partials
  k_gemm<128, 64, false, true><<<dim3(P2_ / 128, 1), 256, 0, stream>>>(
      feat, wbb + WO1, b1, nullptr, nullptr, part, h1);
  k_red <<<dim3(1, 32), 256, 0, stream>>>(part, P2_ / 128, part2);
  k_bnab<<<1, 256, 0, stream>>>(part2, 32, g1, be1, Aall + SO1, Ball + SO1, 1.f / P2_);
  k_apply_max<64><<<P1_ * 16 / 256, 256, 0, stream>>>(h1, Aall + SO1, Ball + SO1, xcat, 0);

  // layer 2: act(h1) x w2 -> h2 (raw) + stats partials
  k_gemm<64, 64, true, true><<<dim3(P2_ / 128, 1), 256, 0, stream>>>(
      h1, wbb + WO2, b2, Aall + SO1, Ball + SO1, part, h2);
  k_red <<<dim3(1, 32), 256, 0, stream>>>(part, P2_ / 128, part2);
  k_bnab<<<1, 256, 0, stream>>>(part2, 32, g2, be2, Aall + SO2, Ball + SO2, 1.f / P2_);
  k_apply_max<64><<<P1_ * 16 / 256, 256, 0, stream>>>(h2, Aall + SO2, Ball + SO2, xcat, 64);

  // layer 3: act(h2) x w3 -> h3 (raw) + stats partials
  k_gemm<64, 128, true, true><<<dim3(P2_ / 128, 2), 256, 0, stream>>>(
      h2, wbb + WO3, b3, Aall + SO2, Ball + SO2, part, h3);
  k_red <<<dim3(2, 32), 256, 0, stream>>>(part, P2_ / 128, part2);
  k_bnab<<<2, 256, 0, stream>>>(part2, 32, g3, be3, Aall + SO3, Ball + SO3, 1.f / P2_);
  k_apply_max<128><<<P1_ * 32 / 256, 256, 0, stream>>>(h3, Aall + SO3, Ball + SO3, xcat, 128);

  // layer 4: act(h3) x w4 -> h4 (raw) + stats partials
  k_gemm<128, 256, true, true><<<dim3(P2_ / 128, 4), 256, 0, stream>>>(
      h3, wbb + WO4, b4, Aall + SO3, Ball + SO3, part, h4);
  k_red <<<dim3(4, 32), 256, 0, stream>>>(part, P2_ / 128, part2);
  k_bnab<<<4, 256, 0, stream>>>(part2, 32, g4, be4, Aall + SO4, Ball + SO4, 1.f / P2_);
  k_apply_max<256><<<P1_ * 64 / 256, 256, 0, stream>>>(h4, Aall + SO4, Ball + SO4, xcat, 256);

  // layer 5: xcat x w5 -> h5 (raw) + stats partials; K=512 panels (NB=64: direct)
  k_gemm<512, 256, false, true><<<dim3(P1_ / 128, 4), 256, 0, stream>>>(
      xcat, wbb + WO5, b5, nullptr, nullptr, part, h5);
  k_bnab<<<4, 256, 0, stream>>>(part, P1_ / 128, g5, be5, Aall + SO5, Ball + SO5, 1.f / P1_);

  // layer 6: act(h5) x w6 -> h6 (raw) + stats partials; K=256 panels (NB=64: direct)
  k_gemm<256, 1024, true, true><<<dim3(P1_ / 128, 16), 256, 0, stream>>>(
      h5, wbb + WO6, b6, Aall + SO5, Ball + SO5, part, h6);
  k_bnab<<<16, 256, 0, stream>>>(part, P1_ / 128, g6, be6, Aall + SO6, Ball + SO6, 1.f / P1_);
  k_apply_out<<<P1_ * 256 / 256, 256, 0, stream>>>(h6, Aall + SO6, Ball + SO6, out);

  (void)in_sizes; (void)n_in; (void)out_size; (void)ws_size;
}